// Round 13
// baseline (1064.950 us; speedup 1.0000x reference)
//
#include <hip/hip_runtime.h>
#include <math.h>

#define BN 8
#define NP 2048
#define KNN 16
#define NL 4
#define NH 8

typedef __attribute__((ext_vector_type(8))) short bf16x8;
typedef __attribute__((ext_vector_type(4))) float f32x4;

__device__ __forceinline__ unsigned short f2bf(float f) {
    unsigned u = __float_as_uint(f);
    unsigned r = (u + 0x7FFFu + ((u >> 16) & 1u)) >> 16;
    return (unsigned short)r;
}
__device__ __forceinline__ float bf2f(unsigned short s) {
    return __uint_as_float(((unsigned)s) << 16);
}
__device__ __forceinline__ unsigned fmono(float f) {
    unsigned u = __float_as_uint(f);
    return (u & 0x80000000u) ? ~u : (u | 0x80000000u);
}
__device__ __forceinline__ float funmono(unsigned k) {
    return (k & 0x80000000u) ? __uint_as_float(k ^ 0x80000000u) : __uint_as_float(~k);
}

// ---------------------------------------------------------------- knn v6 (verified R10/R11)
__device__ __forceinline__ void bsort16_u32(unsigned (&a)[16]) {
    #pragma unroll
    for (int k = 2; k <= 16; k <<= 1) {
        #pragma unroll
        for (int j = k >> 1; j > 0; j >>= 1) {
            #pragma unroll
            for (int i = 0; i < 16; ++i) {
                int ix = i ^ j;
                if (ix > i) {
                    unsigned xv = a[i], yv = a[ix];
                    unsigned lo = xv < yv ? xv : yv, hi = xv < yv ? yv : xv;
                    if ((i & k) == 0) { a[i] = lo; a[ix] = hi; }
                    else              { a[i] = hi; a[ix] = lo; }
                }
            }
        }
    }
}

__device__ __forceinline__ void bclean16(unsigned (&m)[16]) {
    #pragma unroll
    for (int j = 8; j > 0; j >>= 1) {
        #pragma unroll
        for (int i = 0; i < 16; ++i) {
            if ((i & j) == 0) {
                unsigned xv = m[i], yv = m[i + j];
                m[i] = xv < yv ? xv : yv;
                m[i + j] = xv < yv ? yv : xv;
            }
        }
    }
}

__global__ __launch_bounds__(256) void knn_kernel(const float* __restrict__ x, int* __restrict__ idxout) {
    __shared__ unsigned klds[4][2048];
    __shared__ unsigned short tbuf[4][64];
    int tid = threadIdx.x;
    int wv = tid >> 6, lane = tid & 63;
    int p = blockIdx.x * 4 + wv;
    int b = p >> 11, n = p & 2047;
    const float* xb = x + (size_t)b * NP * 3;
    float cx = xb[n * 3 + 0], cy = xb[n * 3 + 1], cz = xb[n * 3 + 2];
    float xn = cx * cx + cy * cy + cz * cz;
    unsigned sa[16], sb[16];
    #pragma unroll
    for (int t = 0; t < 32; ++t) {
        int m = (t << 6) | lane;
        float mx = xb[m * 3 + 0], my = xb[m * 3 + 1], mz = xb[m * 3 + 2];
        float xxm = mx * mx + my * my + mz * mz;
        float inner = cx * mx + cy * my + cz * mz;
        float dd = 2.0f * inner - xn - xxm;
        unsigned u = __float_as_uint(dd);
        u = (u & 0x80000000u) ? ~u : (u | 0x80000000u);
        klds[wv][(t << 6) | lane] = u;
        if (t < 16) sa[t] = u; else sb[t - 16] = u;
    }
    bsort16_u32(sa);
    bsort16_u32(sb);
    unsigned t16[16];
    #pragma unroll
    for (int i = 0; i < 16; ++i) {
        unsigned v0 = sa[i], v1 = sb[15 - i];
        t16[i] = v0 > v1 ? v0 : v1;
    }
    bclean16(t16);
    #pragma unroll
    for (int off = 1; off <= 32; off <<= 1) {
        unsigned other[16];
        #pragma unroll
        for (int i = 0; i < 16; ++i) other[i] = (unsigned)__shfl_xor((int)t16[i], off);
        unsigned m[16];
        #pragma unroll
        for (int i = 0; i < 16; ++i) {
            unsigned a = t16[i], o = other[15 - i];
            m[i] = a > o ? a : o;
        }
        bclean16(m);
        #pragma unroll
        for (int i = 0; i < 16; ++i) t16[i] = m[i];
    }
    unsigned T = t16[0];
    int* op = idxout + (size_t)p * KNN;
    int gcnt = 0, tcnt = 0;
    unsigned long long lt = (lane == 0) ? 0ull : ((~0ull) >> (64 - lane));
    #pragma unroll
    for (int t = 0; t < 32; ++t) {
        int m = (t << 6) | lane;
        unsigned u = klds[wv][m];
        unsigned long long mg = __ballot(u > T);
        unsigned long long me = __ballot(u == T);
        if (u > T) {
            int pos = gcnt + __popcll(mg & lt);
            if (pos < 16) op[pos] = m;
        } else if (u == T) {
            int pos = tcnt + __popcll(me & lt);
            if (pos < 64) tbuf[wv][pos] = (unsigned short)m;
        }
        gcnt += __popcll(mg);
        tcnt += __popcll(me);
    }
    int need = 16 - gcnt;
    if (need > 0 && lane < need) op[gcnt + lane] = (int)tbuf[wv][lane];
}

// ---------------------------------------------------------------- edge conv + max over k -> hcatT[:,0:64] bf16
__global__ __launch_bounds__(256) void edge_conv_kernel(const float* __restrict__ x, const int* __restrict__ idx,
                                                        const float* __restrict__ Wec, const float* __restrict__ bec,
                                                        unsigned short* __restrict__ hcatT) {
    int tid = threadIdx.x;
    int g = tid >> 6, o = tid & 63;
    int p = blockIdx.x * 4 + g;
    int b = p >> 11;
    __shared__ float nb[4][KNN][3];
    __shared__ float ctr[4][3];
    if (o < KNN) {
        int j = idx[(size_t)p * KNN + o];
        const float* xp = x + ((size_t)b * NP + j) * 3;
        nb[g][o][0] = xp[0]; nb[g][o][1] = xp[1]; nb[g][o][2] = xp[2];
    }
    if (o >= KNN && o < KNN + 3) ctr[g][o - KNN] = x[(size_t)p * 3 + (o - KNN)];
    __syncthreads();
    float w0 = Wec[o * 6 + 0], w1 = Wec[o * 6 + 1], w2 = Wec[o * 6 + 2];
    float w3 = Wec[o * 6 + 3], w4 = Wec[o * 6 + 4], w5 = Wec[o * 6 + 5];
    float c0 = ctr[g][0], c1 = ctr[g][1], c2 = ctr[g][2];
    float base = bec[o] + w3 * c0 + w4 * c1 + w5 * c2;
    float m = -3.4e38f;
    #pragma unroll
    for (int k = 0; k < KNN; ++k) {
        float v = base + w0 * (nb[g][k][0] - c0) + w1 * (nb[g][k][1] - c1) + w2 * (nb[g][k][2] - c2);
        v = v > 0.f ? v : 0.2f * v;
        m = fmaxf(m, v);
    }
    hcatT[(size_t)p * 512 + o] = f2bf(m);
}

// ---------------------------------------------------------------- graph max pool, bf16 [pt][ch] -> bf16 [pt][C]
__global__ __launch_bounds__(256) void pool_bf16_kernel(const unsigned short* __restrict__ src, int s_coff,
                                                        const int* __restrict__ idx,
                                                        unsigned short* __restrict__ dst, int C) {
    int tid = threadIdx.x, wv = tid >> 6, lane = tid & 63;
    int p = blockIdx.x * 4 + wv;
    int b = p >> 11;
    const int* ip = idx + (size_t)p * KNN;
    const unsigned short* sb = src + (size_t)b * NP * 512 + s_coff;
    for (int c0 = 0; c0 < C; c0 += 64) {
        int ch = c0 + lane;
        float m = -3.4e38f;
        #pragma unroll
        for (int k = 0; k < KNN; ++k) {
            int j = ip[k];
            m = fmaxf(m, bf2f(sb[(size_t)j * 512 + ch]));
        }
        dst[(size_t)p * C + ch] = f2bf(m);
    }
}

// ---------------------------------------------------------------- conv1 MFMA: 128pts x 64ch, K=64 (R11 epilogue)
__global__ __launch_bounds__(256) void mfma_conv64_kernel(const unsigned short* __restrict__ A,
                                                          const unsigned short* __restrict__ W,
                                                          const float* __restrict__ bias,
                                                          unsigned short* __restrict__ hcatT, int coff) {
    __shared__ unsigned short As[128][72];
    __shared__ unsigned short Bs[64][72];
    int m0 = blockIdx.x * 128, b = blockIdx.z;
    int tid = threadIdx.x;
    int lane = tid & 63, wave = tid >> 6;
    int wr = wave >> 1, wc = wave & 1;
    int quad = lane >> 4, l16 = lane & 15;
    {
        int r = tid >> 1, s = (tid & 1) * 32;
        const unsigned short* ap = A + (size_t)b * NP * 64 + (size_t)(m0 + r) * 64 + s;
        uint4 v0 = *(const uint4*)(ap);
        uint4 v1 = *(const uint4*)(ap + 8);
        uint4 v2 = *(const uint4*)(ap + 16);
        uint4 v3 = *(const uint4*)(ap + 24);
        *(uint4*)&As[r][s] = v0; *(uint4*)&As[r][s + 8] = v1;
        *(uint4*)&As[r][s + 16] = v2; *(uint4*)&As[r][s + 24] = v3;
    }
    {
        int r = tid >> 2, s = (tid & 3) * 16;
        const unsigned short* wp = W + r * 64 + s;
        *(uint4*)&Bs[r][s] = *(const uint4*)wp;
        *(uint4*)&Bs[r][s + 8] = *(const uint4*)(wp + 8);
    }
    __syncthreads();
    f32x4 acc[4][2] = {};
    #pragma unroll
    for (int k0 = 0; k0 < 64; k0 += 32) {
        bf16x8 af[4], bfv[2];
        #pragma unroll
        for (int i = 0; i < 4; ++i) af[i] = *(const bf16x8*)&As[wr * 64 + i * 16 + l16][k0 + quad * 8];
        #pragma unroll
        for (int j = 0; j < 2; ++j) bfv[j] = *(const bf16x8*)&Bs[wc * 32 + j * 16 + l16][k0 + quad * 8];
        #pragma unroll
        for (int i = 0; i < 4; ++i)
            #pragma unroll
            for (int j = 0; j < 2; ++j)
                acc[i][j] = __builtin_amdgcn_mfma_f32_16x16x32_bf16(af[i], bfv[j], acc[i][j], 0, 0, 0);
    }
    #pragma unroll
    for (int i = 0; i < 4; ++i) {
        #pragma unroll
        for (int r = 0; r < 4; ++r) {
            int pt = m0 + wr * 64 + i * 16 + quad * 4 + r;
            #pragma unroll
            for (int j = 0; j < 2; ++j) {
                int ch = wc * 32 + j * 16 + l16;
                float v = acc[i][j][r] + bias[ch];
                v = v > 0.f ? v : 0.2f * v;
                hcatT[((size_t)b * NP + pt) * 512 + coff + ch] = f2bf(v);
            }
        }
    }
}

// ---------------------------------------------------------------- weight/bias cast + xm init (one launch)
__global__ __launch_bounds__(256) void wcast_kernel(const float* __restrict__ Wf, const float* __restrict__ Wc3,
                                                    const float* __restrict__ Wk, const float* __restrict__ Wv,
                                                    const float* __restrict__ bk, const float* __restrict__ bv,
                                                    const float* __restrict__ Wc1, const float* __restrict__ Wc2,
                                                    unsigned short* __restrict__ WfB, unsigned short* __restrict__ Wc3B,
                                                    unsigned short* __restrict__ WkvB, float* __restrict__ bkv,
                                                    unsigned short* __restrict__ Wc1B, unsigned short* __restrict__ Wc2B,
                                                    unsigned* __restrict__ xmk) {
    int id = blockIdx.x * 256 + threadIdx.x;
    if (id < 262144) { WfB[id] = f2bf(Wf[id]); return; }
    int j = id - 262144;
    if (j < 32768) { Wc3B[j] = f2bf(Wc3[j]); return; }
    j -= 32768;
    if (j < 524288) {
        int l = j >> 17, r = j & 131071;
        float v = (r < 65536) ? Wk[(size_t)(l * 2 + 1) * 65536 + r]
                              : Wv[(size_t)(l * 2 + 1) * 65536 + (r - 65536)];
        WkvB[j] = f2bf(v);
        return;
    }
    j -= 524288;
    if (j < 2048) {
        int l = j >> 9, r = j & 511;
        bkv[j] = (r < 256) ? bk[(l * 2 + 1) * 256 + r] : bv[(l * 2 + 1) * 256 + (r - 256)];
        return;
    }
    j -= 2048;
    if (j < 4096) { Wc1B[j] = f2bf(Wc1[j]); return; }
    j -= 4096;
    if (j < 8192) { Wc2B[j] = f2bf(Wc2[j]); return; }
    j -= 8192;
    if (j < 4096) xmk[j] = 0u;
}

// ---------------------------------------------------------------- generic bf16 MFMA GEMM (R11 epilogue + domax)
__global__ __launch_bounds__(256) void mfma_gemm_kernel(const unsigned short* __restrict__ A, size_t a_bstride,
                                                        const unsigned short* __restrict__ B, size_t b_bstride,
                                                        const float* __restrict__ bias, int bias_per_m,
                                                        void* __restrict__ C, size_t c_bstride, int c_rstride,
                                                        int K, int act, int out_bf16,
                                                        unsigned* __restrict__ xmk, int domax) {
    __shared__ unsigned short As[128][40];
    __shared__ unsigned short Bs[128][40];
    int m0 = blockIdx.x * 128, n0 = blockIdx.y * 128, b = blockIdx.z;
    int tid = threadIdx.x;
    int lane = tid & 63, wave = tid >> 6;
    int wr = wave >> 1, wc = wave & 1;
    int quad = lane >> 4, l16 = lane & 15;
    int r0 = tid >> 2, kc0 = (tid & 3) * 8;
    f32x4 acc[4][4] = {};
    const unsigned short* Ab = A + (size_t)b * a_bstride;
    const unsigned short* Bb = B + (size_t)b * b_bstride;
    for (int k0 = 0; k0 < K; k0 += 32) {
        uint4 a0 = *(const uint4*)(Ab + (size_t)(m0 + r0) * K + k0 + kc0);
        uint4 a1 = *(const uint4*)(Ab + (size_t)(m0 + r0 + 64) * K + k0 + kc0);
        uint4 b0 = *(const uint4*)(Bb + (size_t)(n0 + r0) * K + k0 + kc0);
        uint4 b1 = *(const uint4*)(Bb + (size_t)(n0 + r0 + 64) * K + k0 + kc0);
        __syncthreads();
        *(uint4*)&As[r0][kc0] = a0;
        *(uint4*)&As[r0 + 64][kc0] = a1;
        *(uint4*)&Bs[r0][kc0] = b0;
        *(uint4*)&Bs[r0 + 64][kc0] = b1;
        __syncthreads();
        bf16x8 af[4], bfv[4];
        #pragma unroll
        for (int i = 0; i < 4; ++i) af[i] = *(const bf16x8*)&As[wr * 64 + i * 16 + l16][quad * 8];
        #pragma unroll
        for (int j = 0; j < 4; ++j) bfv[j] = *(const bf16x8*)&Bs[wc * 64 + j * 16 + l16][quad * 8];
        #pragma unroll
        for (int i = 0; i < 4; ++i)
            #pragma unroll
            for (int j = 0; j < 4; ++j)
                acc[i][j] = __builtin_amdgcn_mfma_f32_16x16x32_bf16(af[i], bfv[j], acc[i][j], 0, 0, 0);
    }
    if (domax) {
        #pragma unroll
        for (int i = 0; i < 4; ++i) {
            #pragma unroll
            for (int r = 0; r < 4; ++r) {
                int m = m0 + wr * 64 + i * 16 + quad * 4 + r;
                float v = fmaxf(fmaxf(acc[i][0][r], acc[i][1][r]), fmaxf(acc[i][2][r], acc[i][3][r]));
                v += bias[m];
                #pragma unroll
                for (int off = 1; off <= 8; off <<= 1) v = fmaxf(v, __shfl_xor(v, off));
                if (l16 == 0) atomicMax(&xmk[(size_t)b * 512 + m], fmono(v));
            }
        }
        return;
    }
    #pragma unroll
    for (int i = 0; i < 4; ++i) {
        #pragma unroll
        for (int r = 0; r < 4; ++r) {
            int m = m0 + wr * 64 + i * 16 + quad * 4 + r;
            float bm = bias_per_m ? bias[m] : 0.f;
            #pragma unroll
            for (int j = 0; j < 4; ++j) {
                int n = n0 + wc * 64 + j * 16 + l16;
                float v = acc[i][j][r] + (bias_per_m ? bm : bias[n]);
                if (act) v = v > 0.f ? v : 0.2f * v;
                size_t off = (size_t)b * c_bstride + (size_t)m * c_rstride + n;
                if (out_bf16) ((unsigned short*)C)[off] = f2bf(v);
                else          ((float*)C)[off] = v;
            }
        }
    }
}

// ---------------------------------------------------------------- KV for ALL layers (R11 epilogue)
__global__ __launch_bounds__(256) void mfma_kv_all_kernel(const unsigned short* __restrict__ A,
                                                          const unsigned short* __restrict__ W,
                                                          const float* __restrict__ bkv,
                                                          unsigned short* __restrict__ KVall) {
    __shared__ unsigned short As[128][40];
    __shared__ unsigned short Bs[128][40];
    int m0 = blockIdx.x * 128;
    int nb = blockIdx.y & 3, l = blockIdx.y >> 2;
    int n0 = nb * 128;
    int b = blockIdx.z;
    int tid = threadIdx.x;
    int lane = tid & 63, wave = tid >> 6;
    int wr = wave >> 1, wc = wave & 1;
    int quad = lane >> 4, l16 = lane & 15;
    int r0 = tid >> 2, kc0 = (tid & 3) * 8;
    f32x4 acc[4][4] = {};
    const unsigned short* Ab = A + (size_t)b * NP * 256;
    const unsigned short* Bb = W + (size_t)l * 131072;
    const float* bias = bkv + l * 512;
    for (int k0 = 0; k0 < 256; k0 += 32) {
        uint4 a0 = *(const uint4*)(Ab + (size_t)(m0 + r0) * 256 + k0 + kc0);
        uint4 a1 = *(const uint4*)(Ab + (size_t)(m0 + r0 + 64) * 256 + k0 + kc0);
        uint4 b0 = *(const uint4*)(Bb + (size_t)(n0 + r0) * 256 + k0 + kc0);
        uint4 b1 = *(const uint4*)(Bb + (size_t)(n0 + r0 + 64) * 256 + k0 + kc0);
        __syncthreads();
        *(uint4*)&As[r0][kc0] = a0;
        *(uint4*)&As[r0 + 64][kc0] = a1;
        *(uint4*)&Bs[r0][kc0] = b0;
        *(uint4*)&Bs[r0 + 64][kc0] = b1;
        __syncthreads();
        bf16x8 af[4], bfv[4];
        #pragma unroll
        for (int i = 0; i < 4; ++i) af[i] = *(const bf16x8*)&As[wr * 64 + i * 16 + l16][quad * 8];
        #pragma unroll
        for (int j = 0; j < 4; ++j) bfv[j] = *(const bf16x8*)&Bs[wc * 64 + j * 16 + l16][quad * 8];
        #pragma unroll
        for (int i = 0; i < 4; ++i)
            #pragma unroll
            for (int j = 0; j < 4; ++j)
                acc[i][j] = __builtin_amdgcn_mfma_f32_16x16x32_bf16(af[i], bfv[j], acc[i][j], 0, 0, 0);
    }
    unsigned short* Cb = KVall + ((size_t)l * BN + b) * NP * 512;
    #pragma unroll
    for (int i = 0; i < 4; ++i) {
        #pragma unroll
        for (int r = 0; r < 4; ++r) {
            int m = m0 + wr * 64 + i * 16 + quad * 4 + r;
            #pragma unroll
            for (int j = 0; j < 4; ++j) {
                int n = n0 + wc * 64 + j * 16 + l16;
                Cb[(size_t)m * 512 + n] = f2bf(acc[i][j][r] + bias[n]);
            }
        }
    }
}

// ---------------------------------------------------------------- q0 = act(unmono(xm).reshape(B,8,64) @ Wpc.T + bpc)
__global__ __launch_bounds__(256) void pc_kernel(const unsigned* __restrict__ xmk, const float* __restrict__ Wpc,
                                                 const float* __restrict__ bpc, float* __restrict__ q) {
    int id = blockIdx.x * 256 + threadIdx.x;
    int p = id & 255;
    int rowi = id >> 8;
    int b = rowi >> 3, i = rowi & 7;
    const unsigned* xr = xmk + b * 512 + i * 64;
    const float* w = Wpc + (size_t)p * 64;
    float acc = bpc[p];
    #pragma unroll
    for (int e = 0; e < 64; ++e) acc += funmono(xr[e]) * w[e];
    q[id] = acc > 0.f ? acc : 0.2f * acc;
}

// ---------------------------------------------------------------- memB = bf16(act(x @ Wpi.T + bpi))
__global__ __launch_bounds__(256) void mem_kernel(const float* __restrict__ x, const float* __restrict__ Wpi,
                                                  const float* __restrict__ bpi, unsigned short* __restrict__ memB) {
    size_t id = (size_t)blockIdx.x * 256 + threadIdx.x;
    int p = (int)(id & 255);
    size_t pt = id >> 8;
    float x0 = x[pt * 3 + 0], x1 = x[pt * 3 + 1], x2 = x[pt * 3 + 2];
    float v = bpi[p] + x0 * Wpi[p * 3 + 0] + x1 * Wpi[p * 3 + 1] + x2 * Wpi[p * 3 + 2];
    v = v > 0.f ? v : 0.2f * v;
    memB[id] = f2bf(v);
}

// ---------------------------------------------------------------- QKV + self-attn + O-proj + res + LN + cross-Q-proj
__global__ __launch_bounds__(256) void attn_ln_kernel(const float* __restrict__ in,
                                                      const float* __restrict__ Wq0, const float* __restrict__ bq0,
                                                      const float* __restrict__ Wk0, const float* __restrict__ bk0,
                                                      const float* __restrict__ Wv0, const float* __restrict__ bv0,
                                                      const float* __restrict__ Wo, const float* __restrict__ bo,
                                                      const float* __restrict__ g, const float* __restrict__ bt,
                                                      const float* __restrict__ Wq1, const float* __restrict__ bq1,
                                                      float* __restrict__ out, float* __restrict__ Qc) {
    int row = blockIdx.x, tid = threadIdx.x;
    int b = row >> 3, ri = row & 7;
    __shared__ __align__(16) float qin[8][256];
    __shared__ float Kl[2048], Vl[2048], qr[256];
    __shared__ float sc[64];
    __shared__ __align__(16) float r[256];
    __shared__ __align__(16) float aout[256];
    __shared__ float red[256];
    for (int t = tid; t < 2048; t += 256) qin[t >> 8][t & 255] = in[(size_t)b * 2048 + t];
    __syncthreads();
    // Q for this row (identical accumulation order to old qkv_proj)
    {
        const float4* w4 = (const float4*)(Wq0 + (size_t)tid * 256);
        const float4* r4 = (const float4*)qin[ri];
        float acc = bq0[tid];
        #pragma unroll 8
        for (int c = 0; c < 64; ++c) {
            float4 a = r4[c], wv = w4[c];
            acc += a.x * wv.x + a.y * wv.y + a.z * wv.z + a.w * wv.w;
        }
        qr[tid] = acc;
    }
    // K, V for the batch's 8 rows
    for (int k = 0; k < 8; ++k) {
        const float4* rk = (const float4*)qin[k];
        const float4* wk = (const float4*)(Wk0 + (size_t)tid * 256);
        float acck = bk0[tid];
        #pragma unroll 8
        for (int c = 0; c < 64; ++c) {
            float4 a = rk[c], wv = wk[c];
            acck += a.x * wv.x + a.y * wv.y + a.z * wv.z + a.w * wv.w;
        }
        Kl[k * 256 + tid] = acck;
        const float4* wvp = (const float4*)(Wv0 + (size_t)tid * 256);
        float accv = bv0[tid];
        #pragma unroll 8
        for (int c = 0; c < 64; ++c) {
            float4 a = rk[c], wv = wvp[c];
            accv += a.x * wv.x + a.y * wv.y + a.z * wv.z + a.w * wv.w;
        }
        Vl[k * 256 + tid] = accv;
    }
    __syncthreads();
    const float scale = 0.17677669529663687f;
    if (tid < 64) {
        int h = tid >> 3, k = tid & 7;
        float dot = 0.f;
        #pragma unroll
        for (int d = 0; d < 32; ++d) dot += qr[h * 32 + d] * Kl[k * 256 + h * 32 + d];
        sc[tid] = dot * scale;
    }
    __syncthreads();
    if (tid < 8) {
        float* p = sc + tid * 8;
        float m = -3.4e38f;
        #pragma unroll
        for (int k = 0; k < 8; ++k) m = fmaxf(m, p[k]);
        float s = 0.f;
        #pragma unroll
        for (int k = 0; k < 8; ++k) { p[k] = __expf(p[k] - m); s += p[k]; }
        float inv = 1.f / s;
        #pragma unroll
        for (int k = 0; k < 8; ++k) p[k] *= inv;
    }
    __syncthreads();
    {
        int h = tid >> 5;
        float acc = 0.f;
        #pragma unroll
        for (int k = 0; k < 8; ++k) acc += sc[h * 8 + k] * Vl[k * 256 + tid];
        r[tid] = acc;
    }
    __syncthreads();
    const float4* w4 = (const float4*)(Wo + (size_t)tid * 256);
    const float4* r4 = (const float4*)r;
    float acc = bo[tid];
    #pragma unroll 8
    for (int c = 0; c < 64; ++c) {
        float4 a = r4[c], wv = w4[c];
        acc += a.x * wv.x + a.y * wv.y + a.z * wv.z + a.w * wv.w;
    }
    float v = qin[ri][tid] + acc;
    red[tid] = v; __syncthreads();
    for (int s = 128; s; s >>= 1) { if (tid < s) red[tid] += red[tid + s]; __syncthreads(); }
    float mean = red[0] * (1.0f / 256.0f);
    __syncthreads();
    float dv = v - mean;
    red[tid] = dv * dv; __syncthreads();
    for (int s = 128; s; s >>= 1) { if (tid < s) red[tid] += red[tid + s]; __syncthreads(); }
    float var = red[0] * (1.0f / 256.0f);
    float oln = g[tid] * dv * rsqrtf(var + 1e-5f) + bt[tid];
    out[(size_t)row * 256 + tid] = oln;
    aout[tid] = oln;
    __syncthreads();
    {
        const float4* wq4 = (const float4*)(Wq1 + (size_t)tid * 256);
        const float4* a4 = (const float4*)aout;
        float qacc = bq1[tid];
        #pragma unroll 8
        for (int c = 0; c < 64; ++c) {
            float4 a = a4[c], wv = wq4[c];
            qacc += a.x * wv.x + a.y * wv.y + a.z * wv.z + a.w * wv.w;
        }
        Qc[(size_t)row * 256 + tid] = qacc;
    }
}

// ---------------------------------------------------------------- cross-attn pass 1: 16 key-blocks of 128
__global__ __launch_bounds__(256) void ca_part_kernel(const float* __restrict__ Qc,
                                                      const unsigned short* __restrict__ KVl,
                                                      float* __restrict__ part) {
    int kb = blockIdx.x, h = blockIdx.y, b = blockIdx.z;
    int tid = threadIdx.x;
    __shared__ float q[8][32];
    __shared__ __align__(16) float S[8][128];
    __shared__ float om[8][8][32];
    const float scale = 0.17677669529663687f;
    {
        int i = tid >> 5, d = tid & 31;
        q[i][d] = Qc[(size_t)(b * 8 + i) * 256 + h * 32 + d];
    }
    __syncthreads();
    {
        int kk = tid & 127, half = tid >> 7;
        int k = kb * 128 + kk;
        const unsigned short* kp = KVl + ((size_t)b * NP + k) * 512 + h * 32;
        float kd[32];
        #pragma unroll
        for (int u = 0; u < 4; ++u) {
            uint4 raw = *(const uint4*)(kp + u * 8);
            unsigned w0 = raw.x, w1 = raw.y, w2 = raw.z, w3 = raw.w;
            kd[u * 8 + 0] = __uint_as_float(w0 << 16); kd[u * 8 + 1] = __uint_as_float(w0 & 0xFFFF0000u);
            kd[u * 8 + 2] = __uint_as_float(w1 << 16); kd[u * 8 + 3] = __uint_as_float(w1 & 0xFFFF0000u);
            kd[u * 8 + 4] = __uint_as_float(w2 << 16); kd[u * 8 + 5] = __uint_as_float(w2 & 0xFFFF0000u);
            kd[u * 8 + 6] = __uint_as_float(w3 << 16); kd[u * 8 + 7] = __uint_as_float(w3 & 0xFFFF0000u);
        }
        #pragma unroll
        for (int i = 0; i < 4; ++i) {
            int ri = half * 4 + i;
            float dot = 0.f;
            #pragma unroll
            for (int d = 0; d < 32; ++d) dot += q[ri][d] * kd[d];
            S[ri][kk] = dot * scale;
        }
    }
    __syncthreads();
    float* pout = part + (((size_t)(b * NH + h)) * 16 + kb) * 288;
    {
        int i = tid >> 5, l32 = tid & 31;
        float m = -3.4e38f;
        #pragma unroll
        for (int t = 0; t < 4; ++t) m = fmaxf(m, S[i][l32 + t * 32]);
        #pragma unroll
        for (int off = 16; off; off >>= 1) m = fmaxf(m, __shfl_xor(m, off));
        float s = 0.f;
        #pragma unroll
        for (int t = 0; t < 4; ++t) {
            float e = __expf(S[i][l32 + t * 32] - m);
            S[i][l32 + t * 32] = e;
            s += e;
        }
        #pragma unroll
        for (int off = 16; off; off >>= 1) s += __shfl_xor(s, off);
        if (l32 == 0) { pout[i] = m; pout[8 + i] = s; }
    }
    __syncthreads();
    {
        int d = tid & 31, grp = tid >> 5;
        const unsigned short* Vb = KVl + ((size_t)b * NP + kb * 128) * 512 + 256 + h * 32 + d;
        float acc[8] = {};
        #pragma unroll 4
        for (int t = 0; t < 16; ++t) {
            int kk = grp * 16 + t;
            float v = bf2f(Vb[(size_t)kk * 512]);
            #pragma unroll
            for (int i = 0; i < 8; ++i) acc[i] += S[i][kk] * v;
        }
        #pragma unroll
        for (int i = 0; i < 8; ++i) om[grp][i][d] = acc[i];
    }
    __syncthreads();
    {
        int i = tid >> 5, d = tid & 31;
        float sum = 0.f;
        #pragma unroll
        for (int g = 0; g < 8; ++g) sum += om[g][i][d];
        pout[16 + i * 32 + d] = sum;
    }
}

// ---------------------------------------------------------------- combine + O-proj + LN + FF + LN [+ final LN+Wcm]
__global__ __launch_bounds__(256) void combine_ff_kernel(const float* __restrict__ part, const float* __restrict__ Wo,
                                                         const float* __restrict__ bo, const float* __restrict__ res,
                                                         const float* __restrict__ g2, const float* __restrict__ b2t,
                                                         const float* __restrict__ W1, const float* __restrict__ b1,
                                                         const float* __restrict__ W2, const float* __restrict__ b2,
                                                         const float* __restrict__ g3, const float* __restrict__ b3t,
                                                         float* __restrict__ out,
                                                         int is_last, const float* __restrict__ lnfg,
                                                         const float* __restrict__ lnfb, const float* __restrict__ Wcm,
                                                         const float* __restrict__ bcm, float* __restrict__ finout) {
    int row = blockIdx.x, tid = threadIdx.x;
    int b = row >> 3, i = row & 7;
    __shared__ __align__(16) float r[256];
    __shared__ __align__(16) float a[256];
    __shared__ __align__(16) float hbuf[512];
    __shared__ float red[256];
    {
        int h = tid >> 5, d = tid & 31;
        const float* pb = part + (size_t)(b * NH + h) * 16 * 288;
        float M = -3.4e38f;
        #pragma unroll
        for (int kb = 0; kb < 16; ++kb) M = fmaxf(M, pb[kb * 288 + i]);
        float L = 0.f, O = 0.f;
        #pragma unroll
        for (int kb = 0; kb < 16; ++kb) {
            float w = __expf(pb[kb * 288 + i] - M);
            L += pb[kb * 288 + 8 + i] * w;
            O += pb[kb * 288 + 16 + i * 32 + d] * w;
        }
        r[tid] = O / L;
    }
    __syncthreads();
    {
        const float4* w4 = (const float4*)(Wo + (size_t)tid * 256);
        const float4* r4 = (const float4*)r;
        float acc = bo[tid];
        #pragma unroll 8
        for (int c = 0; c < 64; ++c) {
            float4 av = r4[c], wv = w4[c];
            acc += av.x * wv.x + av.y * wv.y + av.z * wv.z + av.w * wv.w;
        }
        float v = res[(size_t)row * 256 + tid] + acc;
        red[tid] = v; __syncthreads();
        for (int s = 128; s; s >>= 1) { if (tid < s) red[tid] += red[tid + s]; __syncthreads(); }
        float mean = red[0] * (1.0f / 256.0f);
        __syncthreads();
        float dv = v - mean;
        red[tid] = dv * dv; __syncthreads();
        for (int s = 128; s; s >>= 1) { if (tid < s) red[tid] += red[tid + s]; __syncthreads(); }
        float var = red[0] * (1.0f / 256.0f);
        a[tid] = g2[tid] * dv * rsqrtf(var + 1e-5f) + b2t[tid];
    }
    __syncthreads();
    {
        const float4* a4 = (const float4*)a;
        #pragma unroll
        for (int half = 0; half < 2; ++half) {
            int o = tid + half * 256;
            const float4* w4 = (const float4*)(W1 + (size_t)o * 256);
            float acc = b1[o];
            #pragma unroll 8
            for (int c = 0; c < 64; ++c) {
                float4 av = a4[c], wv = w4[c];
                acc += av.x * wv.x + av.y * wv.y + av.z * wv.z + av.w * wv.w;
            }
            hbuf[o] = acc > 0.f ? acc : 0.2f * acc;
        }
    }
    __syncthreads();
    float tln;
    {
        const float4* h4 = (const float4*)hbuf;
        const float4* w4 = (const float4*)(W2 + (size_t)tid * 512);
        float acc = b2[tid];
        #pragma unroll 8
        for (int c = 0; c < 128; ++c) {
            float4 av = h4[c], wv = w4[c];
            acc += av.x * wv.x + av.y * wv.y + av.z * wv.z + av.w * wv.w;
        }
        float v = a[tid] + acc;
        red[tid] = v; __syncthreads();
        for (int s = 128; s; s >>= 1) { if (tid < s) red[tid] += red[tid + s]; __syncthreads(); }
        float mean = red[0] * (1.0f / 256.0f);
        __syncthreads();
        float dv = v - mean;
        red[tid] = dv * dv; __syncthreads();
        for (int s = 128; s; s >>= 1) { if (tid < s) red[tid] += red[tid + s]; __syncthreads(); }
        float var = red[0] * (1.0f / 256.0f);
        tln = g3[tid] * dv * rsqrtf(var + 1e-5f) + b3t[tid];
    }
    if (!is_last) {
        out[(size_t)row * 256 + tid] = tln;
        return;
    }
    __syncthreads();
    red[tid] = tln; __syncthreads();
    for (int s = 128; s; s >>= 1) { if (tid < s) red[tid] += red[tid + s]; __syncthreads(); }
    float mean = red[0] * (1.0f / 256.0f);
    __syncthreads();
    float dv = tln - mean;
    red[tid] = dv * dv; __syncthreads();
    for (int s = 128; s; s >>= 1) { if (tid < s) red[tid] += red[tid + s]; __syncthreads(); }
    float var = red[0] * (1.0f / 256.0f);
    a[tid] = lnfg[tid] * dv * rsqrtf(var + 1e-5f) + lnfb[tid];
    __syncthreads();
    if (tid < 64) {
        const float4* w4 = (const float4*)(Wcm + (size_t)tid * 256);
        const float4* a4 = (const float4*)a;
        float acc = bcm[tid];
        #pragma unroll 8
        for (int c = 0; c < 64; ++c) {
            float4 av = a4[c], wv = w4[c];
            acc += av.x * wv.x + av.y * wv.y + av.z * wv.z + av.w * wv.w;
        }
        finout[(size_t)b * 512 + i * 64 + tid] = acc;
    }
}

// ================================================================ host
extern "C" void kernel_launch(void* const* d_in, const int* in_sizes, int n_in,
                              void* d_out, int out_size, void* d_ws, size_t ws_size,
                              hipStream_t stream) {
    const float* x    = (const float*)d_in[0];
    const float* Wec  = (const float*)d_in[1];
    const float* bec  = (const float*)d_in[2];
    const float* Wc1  = (const float*)d_in[3];
    const float* bc1  = (const float*)d_in[4];
    const float* Wc2  = (const float*)d_in[5];
    const float* bc2  = (const float*)d_in[6];
    const float* Wc3  = (const float*)d_in[7];
    const float* bc3  = (const float*)d_in[8];
    const float* Wf   = (const float*)d_in[9];
    const float* bf   = (const float*)d_in[10];
    const float* Wpc  = (const float*)d_in[11];
    const float* bpc  = (const float*)d_in[12];
    const float* Wpi  = (const float*)d_in[13];
    const float* bpi  = (const float*)d_in[14];
    const float* Wq   = (const float*)d_in[15];
    const float* bq   = (const float*)d_in[16];
    const float* Wk   = (const float*)d_in[17];
    const float* bk   = (const float*)d_in[18];
    const float* Wv   = (const float*)d_in[19];
    const float* bv   = (const float*)d_in[20];
    const float* Wo   = (const float*)d_in[21];
    const float* bo   = (const float*)d_in[22];
    const float* ln1g = (const float*)d_in[23];
    const float* ln1b = (const float*)d_in[24];
    const float* ln2g = (const float*)d_in[25];
    const float* ln2b = (const float*)d_in[26];
    const float* Wff1 = (const float*)d_in[27];
    const float* bff1 = (const float*)d_in[28];
    const float* Wff2 = (const float*)d_in[29];
    const float* bff2 = (const float*)d_in[30];
    const float* ln3g = (const float*)d_in[31];
    const float* ln3b = (const float*)d_in[32];
    const float* lnfg = (const float*)d_in[33];
    const float* lnfb = (const float*)d_in[34];
    const float* Wcm  = (const float*)d_in[35];
    const float* bcm  = (const float*)d_in[36];
    float* out = (float*)d_out;

    float* ws = (float*)d_ws;
    size_t off = 0;
    auto alloc = [&](size_t n) { float* p = ws + off; off += (n + 3) & ~(size_t)3; return p; };
    int*            idx   = (int*)alloc((size_t)BN * NP * KNN);
    unsigned short* hcatT = (unsigned short*)alloc((size_t)BN * NP * 512 / 2);
    unsigned short* poolT = (unsigned short*)alloc((size_t)BN * NP * 128 / 2);
    unsigned short* WfB   = (unsigned short*)alloc(262144 / 2);
    unsigned short* Wc1B  = (unsigned short*)alloc(4096 / 2);
    unsigned short* Wc2B  = (unsigned short*)alloc(8192 / 2);
    unsigned short* Wc3B  = (unsigned short*)alloc(32768 / 2);
    unsigned short* WkvB  = (unsigned short*)alloc(524288 / 2);
    float*          bkv   = alloc(2048);
    unsigned short* memB  = (unsigned short*)alloc((size_t)BN * NP * 256 / 2);
    unsigned short* KVall = (unsigned short*)alloc((size_t)NL * BN * NP * 512 / 2);
    unsigned*       xmk   = (unsigned*)alloc((size_t)BN * 512);
    float*          qa    = alloc((size_t)BN * 8 * 256);
    float*          qb    = alloc((size_t)BN * 8 * 256);
    float*          Qc    = alloc((size_t)BN * 8 * 256);
    float*          part  = alloc((size_t)BN * NH * 16 * 288);

    // ---- weight casts + xm-key init (no deps) ----
    wcast_kernel<<<3272, 256, 0, stream>>>(Wf, Wc3, Wk, Wv, bk, bv, Wc1, Wc2,
                                           WfB, Wc3B, WkvB, bkv, Wc1B, Wc2B, xmk);

    // ---- point-cloud encoder (all-bf16 [pt][ch] chain), R11 order ----
    knn_kernel<<<BN * NP / 4, 256, 0, stream>>>(x, idx);
    edge_conv_kernel<<<BN * NP / 4, 256, 0, stream>>>(x, idx, Wec, bec, hcatT);

    pool_bf16_kernel<<<BN * NP / 4, 256, 0, stream>>>(hcatT, 0, idx, poolT, 64);
    mfma_conv64_kernel<<<dim3(NP / 128, 1, BN), 256, 0, stream>>>(poolT, Wc1B, bc1, hcatT, 64);
    pool_bf16_kernel<<<BN * NP / 4, 256, 0, stream>>>(hcatT, 64, idx, poolT, 64);
    mfma_gemm_kernel<<<dim3(NP / 128, 1, BN), 256, 0, stream>>>(poolT, (size_t)NP * 64, Wc2B, 0,
                                                                bc2, 0, (void*)(hcatT + 128), (size_t)NP * 512, 512,
                                                                64, 1, 1, nullptr, 0);
    pool_bf16_kernel<<<BN * NP / 4, 256, 0, stream>>>(hcatT, 128, idx, poolT, 128);
    mfma_gemm_kernel<<<dim3(NP / 128, 2, BN), 256, 0, stream>>>(poolT, (size_t)NP * 128, Wc3B, 0,
                                                                bc3, 0, (void*)(hcatT + 256), (size_t)NP * 512, 512,
                                                                128, 1, 1, nullptr, 0);
    mfma_gemm_kernel<<<dim3(4, NP / 128, BN), 256, 0, stream>>>(WfB, 0, hcatT, (size_t)NP * 512,
                                                                bf, 1, nullptr, 0, 0,
                                                                512, 0, 0, xmk, 1);
    pc_kernel<<<BN * 8, 256, 0, stream>>>(xmk, Wpc, bpc, qa);
    mem_kernel<<<BN * NP, 256, 0, stream>>>(x, Wpi, bpi, memB);
    mfma_kv_all_kernel<<<dim3(NP / 128, 4 * NL, BN), 256, 0, stream>>>(memB, WkvB, bkv, KVall);

    // ---- transformer layers (3 launches/layer) ----
    float* qcur = qa; float* qnxt = qb;
    for (int l = 0; l < NL; ++l) {
        const float* Wq0 = Wq + (size_t)(l * 2 + 0) * 65536; const float* bq0 = bq + (l * 2 + 0) * 256;
        const float* Wk0 = Wk + (size_t)(l * 2 + 0) * 65536; const float* bk0 = bk + (l * 2 + 0) * 256;
        const float* Wv0 = Wv + (size_t)(l * 2 + 0) * 65536; const float* bv0 = bv + (l * 2 + 0) * 256;
        const float* Wo0 = Wo + (size_t)(l * 2 + 0) * 65536; const float* bo0 = bo + (l * 2 + 0) * 256;
        const float* Wq1 = Wq + (size_t)(l * 2 + 1) * 65536; const float* bq1 = bq + (l * 2 + 1) * 256;
        const float* Wo1 = Wo + (size_t)(l * 2 + 1) * 65536; const float* bo1 = bo + (l * 2 + 1) * 256;
        int last = (l == NL - 1);

        attn_ln_kernel<<<BN * 8, 256, 0, stream>>>(qcur, Wq0, bq0, Wk0, bk0, Wv0, bv0, Wo0, bo0,
                                                   ln1g + l * 256, ln1b + l * 256, Wq1, bq1, qnxt, Qc);
        ca_part_kernel<<<dim3(16, NH, BN), 256, 0, stream>>>(Qc, KVall + (size_t)l * BN * NP * 512, part);
        combine_ff_kernel<<<BN * 8, 256, 0, stream>>>(part, Wo1, bo1, qnxt,
                                                      ln2g + l * 256, ln2b + l * 256,
                                                      Wff1 + (size_t)l * 512 * 256, bff1 + l * 512,
                                                      Wff2 + (size_t)l * 256 * 512, bff2 + l * 256,
                                                      ln3g + l * 256, ln3b + l * 256, qcur,
                                                      last, lnfg, lnfb, Wcm, bcm, out);
    }

    (void)in_sizes; (void)n_in; (void)out_size; (void)ws_size; (void)qnxt;
}

// Round 14
// 630.862 us; speedup vs baseline: 1.6881x; 1.6881x over previous
//
#include <hip/hip_runtime.h>
#include <math.h>

#define BN 8
#define NP 2048
#define KNN 16
#define NL 4
#define NH 8

typedef __attribute__((ext_vector_type(8))) short bf16x8;
typedef __attribute__((ext_vector_type(4))) float f32x4;

__device__ __forceinline__ unsigned short f2bf(float f) {
    unsigned u = __float_as_uint(f);
    unsigned r = (u + 0x7FFFu + ((u >> 16) & 1u)) >> 16;
    return (unsigned short)r;
}
__device__ __forceinline__ float bf2f(unsigned short s) {
    return __uint_as_float(((unsigned)s) << 16);
}
__device__ __forceinline__ unsigned fmono(float f) {
    unsigned u = __float_as_uint(f);
    return (u & 0x80000000u) ? ~u : (u | 0x80000000u);
}
__device__ __forceinline__ float funmono(unsigned k) {
    return (k & 0x80000000u) ? __uint_as_float(k ^ 0x80000000u) : __uint_as_float(~k);
}

// ---------------------------------------------------------------- knn v6 (verified R10/R11)
__device__ __forceinline__ void bsort16_u32(unsigned (&a)[16]) {
    #pragma unroll
    for (int k = 2; k <= 16; k <<= 1) {
        #pragma unroll
        for (int j = k >> 1; j > 0; j >>= 1) {
            #pragma unroll
            for (int i = 0; i < 16; ++i) {
                int ix = i ^ j;
                if (ix > i) {
                    unsigned xv = a[i], yv = a[ix];
                    unsigned lo = xv < yv ? xv : yv, hi = xv < yv ? yv : xv;
                    if ((i & k) == 0) { a[i] = lo; a[ix] = hi; }
                    else              { a[i] = hi; a[ix] = lo; }
                }
            }
        }
    }
}

__device__ __forceinline__ void bclean16(unsigned (&m)[16]) {
    #pragma unroll
    for (int j = 8; j > 0; j >>= 1) {
        #pragma unroll
        for (int i = 0; i < 16; ++i) {
            if ((i & j) == 0) {
                unsigned xv = m[i], yv = m[i + j];
                m[i] = xv < yv ? xv : yv;
                m[i + j] = xv < yv ? yv : xv;
            }
        }
    }
}

__global__ __launch_bounds__(256) void knn_kernel(const float* __restrict__ x, int* __restrict__ idxout) {
    __shared__ unsigned klds[4][2048];
    __shared__ unsigned short tbuf[4][64];
    int tid = threadIdx.x;
    int wv = tid >> 6, lane = tid & 63;
    int p = blockIdx.x * 4 + wv;
    int b = p >> 11, n = p & 2047;
    const float* xb = x + (size_t)b * NP * 3;
    float cx = xb[n * 3 + 0], cy = xb[n * 3 + 1], cz = xb[n * 3 + 2];
    float xn = cx * cx + cy * cy + cz * cz;
    unsigned sa[16], sb[16];
    #pragma unroll
    for (int t = 0; t < 32; ++t) {
        int m = (t << 6) | lane;
        float mx = xb[m * 3 + 0], my = xb[m * 3 + 1], mz = xb[m * 3 + 2];
        float xxm = mx * mx + my * my + mz * mz;
        float inner = cx * mx + cy * my + cz * mz;
        float dd = 2.0f * inner - xn - xxm;
        unsigned u = __float_as_uint(dd);
        u = (u & 0x80000000u) ? ~u : (u | 0x80000000u);
        klds[wv][(t << 6) | lane] = u;
        if (t < 16) sa[t] = u; else sb[t - 16] = u;
    }
    bsort16_u32(sa);
    bsort16_u32(sb);
    unsigned t16[16];
    #pragma unroll
    for (int i = 0; i < 16; ++i) {
        unsigned v0 = sa[i], v1 = sb[15 - i];
        t16[i] = v0 > v1 ? v0 : v1;
    }
    bclean16(t16);
    #pragma unroll
    for (int off = 1; off <= 32; off <<= 1) {
        unsigned other[16];
        #pragma unroll
        for (int i = 0; i < 16; ++i) other[i] = (unsigned)__shfl_xor((int)t16[i], off);
        unsigned m[16];
        #pragma unroll
        for (int i = 0; i < 16; ++i) {
            unsigned a = t16[i], o = other[15 - i];
            m[i] = a > o ? a : o;
        }
        bclean16(m);
        #pragma unroll
        for (int i = 0; i < 16; ++i) t16[i] = m[i];
    }
    unsigned T = t16[0];
    int* op = idxout + (size_t)p * KNN;
    int gcnt = 0, tcnt = 0;
    unsigned long long lt = (lane == 0) ? 0ull : ((~0ull) >> (64 - lane));
    #pragma unroll
    for (int t = 0; t < 32; ++t) {
        int m = (t << 6) | lane;
        unsigned u = klds[wv][m];
        unsigned long long mg = __ballot(u > T);
        unsigned long long me = __ballot(u == T);
        if (u > T) {
            int pos = gcnt + __popcll(mg & lt);
            if (pos < 16) op[pos] = m;
        } else if (u == T) {
            int pos = tcnt + __popcll(me & lt);
            if (pos < 64) tbuf[wv][pos] = (unsigned short)m;
        }
        gcnt += __popcll(mg);
        tcnt += __popcll(me);
    }
    int need = 16 - gcnt;
    if (need > 0 && lane < need) op[gcnt + lane] = (int)tbuf[wv][lane];
}

// ---------------------------------------------------------------- edge conv + max over k -> hcatT[:,0:64] bf16
__global__ __launch_bounds__(256) void edge_conv_kernel(const float* __restrict__ x, const int* __restrict__ idx,
                                                        const float* __restrict__ Wec, const float* __restrict__ bec,
                                                        unsigned short* __restrict__ hcatT) {
    int tid = threadIdx.x;
    int g = tid >> 6, o = tid & 63;
    int p = blockIdx.x * 4 + g;
    int b = p >> 11;
    __shared__ float nb[4][KNN][3];
    __shared__ float ctr[4][3];
    if (o < KNN) {
        int j = idx[(size_t)p * KNN + o];
        const float* xp = x + ((size_t)b * NP + j) * 3;
        nb[g][o][0] = xp[0]; nb[g][o][1] = xp[1]; nb[g][o][2] = xp[2];
    }
    if (o >= KNN && o < KNN + 3) ctr[g][o - KNN] = x[(size_t)p * 3 + (o - KNN)];
    __syncthreads();
    float w0 = Wec[o * 6 + 0], w1 = Wec[o * 6 + 1], w2 = Wec[o * 6 + 2];
    float w3 = Wec[o * 6 + 3], w4 = Wec[o * 6 + 4], w5 = Wec[o * 6 + 5];
    float c0 = ctr[g][0], c1 = ctr[g][1], c2 = ctr[g][2];
    float base = bec[o] + w3 * c0 + w4 * c1 + w5 * c2;
    float m = -3.4e38f;
    #pragma unroll
    for (int k = 0; k < KNN; ++k) {
        float v = base + w0 * (nb[g][k][0] - c0) + w1 * (nb[g][k][1] - c1) + w2 * (nb[g][k][2] - c2);
        v = v > 0.f ? v : 0.2f * v;
        m = fmaxf(m, v);
    }
    hcatT[(size_t)p * 512 + o] = f2bf(m);
}

// ---------------------------------------------------------------- graph max pool, bf16 [pt][ch] -> bf16 [pt][C]
__global__ __launch_bounds__(256) void pool_bf16_kernel(const unsigned short* __restrict__ src, int s_coff,
                                                        const int* __restrict__ idx,
                                                        unsigned short* __restrict__ dst, int C) {
    int tid = threadIdx.x, wv = tid >> 6, lane = tid & 63;
    int p = blockIdx.x * 4 + wv;
    int b = p >> 11;
    const int* ip = idx + (size_t)p * KNN;
    const unsigned short* sb = src + (size_t)b * NP * 512 + s_coff;
    for (int c0 = 0; c0 < C; c0 += 64) {
        int ch = c0 + lane;
        float m = -3.4e38f;
        #pragma unroll
        for (int k = 0; k < KNN; ++k) {
            int j = ip[k];
            m = fmaxf(m, bf2f(sb[(size_t)j * 512 + ch]));
        }
        dst[(size_t)p * C + ch] = f2bf(m);
    }
}

// ---------------------------------------------------------------- conv1 MFMA: 128pts x 64ch, K=64 (R11 epilogue)
__global__ __launch_bounds__(256) void mfma_conv64_kernel(const unsigned short* __restrict__ A,
                                                          const unsigned short* __restrict__ W,
                                                          const float* __restrict__ bias,
                                                          unsigned short* __restrict__ hcatT, int coff) {
    __shared__ unsigned short As[128][72];
    __shared__ unsigned short Bs[64][72];
    int m0 = blockIdx.x * 128, b = blockIdx.z;
    int tid = threadIdx.x;
    int lane = tid & 63, wave = tid >> 6;
    int wr = wave >> 1, wc = wave & 1;
    int quad = lane >> 4, l16 = lane & 15;
    {
        int r = tid >> 1, s = (tid & 1) * 32;
        const unsigned short* ap = A + (size_t)b * NP * 64 + (size_t)(m0 + r) * 64 + s;
        uint4 v0 = *(const uint4*)(ap);
        uint4 v1 = *(const uint4*)(ap + 8);
        uint4 v2 = *(const uint4*)(ap + 16);
        uint4 v3 = *(const uint4*)(ap + 24);
        *(uint4*)&As[r][s] = v0; *(uint4*)&As[r][s + 8] = v1;
        *(uint4*)&As[r][s + 16] = v2; *(uint4*)&As[r][s + 24] = v3;
    }
    {
        int r = tid >> 2, s = (tid & 3) * 16;
        const unsigned short* wp = W + r * 64 + s;
        *(uint4*)&Bs[r][s] = *(const uint4*)wp;
        *(uint4*)&Bs[r][s + 8] = *(const uint4*)(wp + 8);
    }
    __syncthreads();
    f32x4 acc[4][2] = {};
    #pragma unroll
    for (int k0 = 0; k0 < 64; k0 += 32) {
        bf16x8 af[4], bfv[2];
        #pragma unroll
        for (int i = 0; i < 4; ++i) af[i] = *(const bf16x8*)&As[wr * 64 + i * 16 + l16][k0 + quad * 8];
        #pragma unroll
        for (int j = 0; j < 2; ++j) bfv[j] = *(const bf16x8*)&Bs[wc * 32 + j * 16 + l16][k0 + quad * 8];
        #pragma unroll
        for (int i = 0; i < 4; ++i)
            #pragma unroll
            for (int j = 0; j < 2; ++j)
                acc[i][j] = __builtin_amdgcn_mfma_f32_16x16x32_bf16(af[i], bfv[j], acc[i][j], 0, 0, 0);
    }
    #pragma unroll
    for (int i = 0; i < 4; ++i) {
        #pragma unroll
        for (int r = 0; r < 4; ++r) {
            int pt = m0 + wr * 64 + i * 16 + quad * 4 + r;
            #pragma unroll
            for (int j = 0; j < 2; ++j) {
                int ch = wc * 32 + j * 16 + l16;
                float v = acc[i][j][r] + bias[ch];
                v = v > 0.f ? v : 0.2f * v;
                hcatT[((size_t)b * NP + pt) * 512 + coff + ch] = f2bf(v);
            }
        }
    }
}

// ---------------------------------------------------------------- weight/bias cast + xm init (one launch)
__global__ __launch_bounds__(256) void wcast_kernel(const float* __restrict__ Wf, const float* __restrict__ Wc3,
                                                    const float* __restrict__ Wk, const float* __restrict__ Wv,
                                                    const float* __restrict__ bk, const float* __restrict__ bv,
                                                    const float* __restrict__ Wc1, const float* __restrict__ Wc2,
                                                    unsigned short* __restrict__ WfB, unsigned short* __restrict__ Wc3B,
                                                    unsigned short* __restrict__ WkvB, float* __restrict__ bkv,
                                                    unsigned short* __restrict__ Wc1B, unsigned short* __restrict__ Wc2B,
                                                    unsigned* __restrict__ xmk) {
    int id = blockIdx.x * 256 + threadIdx.x;
    if (id < 262144) { WfB[id] = f2bf(Wf[id]); return; }
    int j = id - 262144;
    if (j < 32768) { Wc3B[j] = f2bf(Wc3[j]); return; }
    j -= 32768;
    if (j < 524288) {
        int l = j >> 17, r = j & 131071;
        float v = (r < 65536) ? Wk[(size_t)(l * 2 + 1) * 65536 + r]
                              : Wv[(size_t)(l * 2 + 1) * 65536 + (r - 65536)];
        WkvB[j] = f2bf(v);
        return;
    }
    j -= 524288;
    if (j < 2048) {
        int l = j >> 9, r = j & 511;
        bkv[j] = (r < 256) ? bk[(l * 2 + 1) * 256 + r] : bv[(l * 2 + 1) * 256 + (r - 256)];
        return;
    }
    j -= 2048;
    if (j < 4096) { Wc1B[j] = f2bf(Wc1[j]); return; }
    j -= 4096;
    if (j < 8192) { Wc2B[j] = f2bf(Wc2[j]); return; }
    j -= 8192;
    if (j < 4096) xmk[j] = 0u;
}

// ---------------------------------------------------------------- generic bf16 MFMA GEMM (R11 epilogue + domax)
__global__ __launch_bounds__(256) void mfma_gemm_kernel(const unsigned short* __restrict__ A, size_t a_bstride,
                                                        const unsigned short* __restrict__ B, size_t b_bstride,
                                                        const float* __restrict__ bias, int bias_per_m,
                                                        void* __restrict__ C, size_t c_bstride, int c_rstride,
                                                        int K, int act, int out_bf16,
                                                        unsigned* __restrict__ xmk, int domax) {
    __shared__ unsigned short As[128][40];
    __shared__ unsigned short Bs[128][40];
    int m0 = blockIdx.x * 128, n0 = blockIdx.y * 128, b = blockIdx.z;
    int tid = threadIdx.x;
    int lane = tid & 63, wave = tid >> 6;
    int wr = wave >> 1, wc = wave & 1;
    int quad = lane >> 4, l16 = lane & 15;
    int r0 = tid >> 2, kc0 = (tid & 3) * 8;
    f32x4 acc[4][4] = {};
    const unsigned short* Ab = A + (size_t)b * a_bstride;
    const unsigned short* Bb = B + (size_t)b * b_bstride;
    for (int k0 = 0; k0 < K; k0 += 32) {
        uint4 a0 = *(const uint4*)(Ab + (size_t)(m0 + r0) * K + k0 + kc0);
        uint4 a1 = *(const uint4*)(Ab + (size_t)(m0 + r0 + 64) * K + k0 + kc0);
        uint4 b0 = *(const uint4*)(Bb + (size_t)(n0 + r0) * K + k0 + kc0);
        uint4 b1 = *(const uint4*)(Bb + (size_t)(n0 + r0 + 64) * K + k0 + kc0);
        __syncthreads();
        *(uint4*)&As[r0][kc0] = a0;
        *(uint4*)&As[r0 + 64][kc0] = a1;
        *(uint4*)&Bs[r0][kc0] = b0;
        *(uint4*)&Bs[r0 + 64][kc0] = b1;
        __syncthreads();
        bf16x8 af[4], bfv[4];
        #pragma unroll
        for (int i = 0; i < 4; ++i) af[i] = *(const bf16x8*)&As[wr * 64 + i * 16 + l16][quad * 8];
        #pragma unroll
        for (int j = 0; j < 4; ++j) bfv[j] = *(const bf16x8*)&Bs[wc * 64 + j * 16 + l16][quad * 8];
        #pragma unroll
        for (int i = 0; i < 4; ++i)
            #pragma unroll
            for (int j = 0; j < 4; ++j)
                acc[i][j] = __builtin_amdgcn_mfma_f32_16x16x32_bf16(af[i], bfv[j], acc[i][j], 0, 0, 0);
    }
    if (domax) {
        #pragma unroll
        for (int i = 0; i < 4; ++i) {
            #pragma unroll
            for (int r = 0; r < 4; ++r) {
                int m = m0 + wr * 64 + i * 16 + quad * 4 + r;
                float v = fmaxf(fmaxf(acc[i][0][r], acc[i][1][r]), fmaxf(acc[i][2][r], acc[i][3][r]));
                v += bias[m];
                #pragma unroll
                for (int off = 1; off <= 8; off <<= 1) v = fmaxf(v, __shfl_xor(v, off));
                if (l16 == 0) atomicMax(&xmk[(size_t)b * 512 + m], fmono(v));
            }
        }
        return;
    }
    #pragma unroll
    for (int i = 0; i < 4; ++i) {
        #pragma unroll
        for (int r = 0; r < 4; ++r) {
            int m = m0 + wr * 64 + i * 16 + quad * 4 + r;
            float bm = bias_per_m ? bias[m] : 0.f;
            #pragma unroll
            for (int j = 0; j < 4; ++j) {
                int n = n0 + wc * 64 + j * 16 + l16;
                float v = acc[i][j][r] + (bias_per_m ? bm : bias[n]);
                if (act) v = v > 0.f ? v : 0.2f * v;
                size_t off = (size_t)b * c_bstride + (size_t)m * c_rstride + n;
                if (out_bf16) ((unsigned short*)C)[off] = f2bf(v);
                else          ((float*)C)[off] = v;
            }
        }
    }
}

// ---------------------------------------------------------------- KV for ALL layers (R11 epilogue)
__global__ __launch_bounds__(256) void mfma_kv_all_kernel(const unsigned short* __restrict__ A,
                                                          const unsigned short* __restrict__ W,
                                                          const float* __restrict__ bkv,
                                                          unsigned short* __restrict__ KVall) {
    __shared__ unsigned short As[128][40];
    __shared__ unsigned short Bs[128][40];
    int m0 = blockIdx.x * 128;
    int nb = blockIdx.y & 3, l = blockIdx.y >> 2;
    int n0 = nb * 128;
    int b = blockIdx.z;
    int tid = threadIdx.x;
    int lane = tid & 63, wave = tid >> 6;
    int wr = wave >> 1, wc = wave & 1;
    int quad = lane >> 4, l16 = lane & 15;
    int r0 = tid >> 2, kc0 = (tid & 3) * 8;
    f32x4 acc[4][4] = {};
    const unsigned short* Ab = A + (size_t)b * NP * 256;
    const unsigned short* Bb = W + (size_t)l * 131072;
    const float* bias = bkv + l * 512;
    for (int k0 = 0; k0 < 256; k0 += 32) {
        uint4 a0 = *(const uint4*)(Ab + (size_t)(m0 + r0) * 256 + k0 + kc0);
        uint4 a1 = *(const uint4*)(Ab + (size_t)(m0 + r0 + 64) * 256 + k0 + kc0);
        uint4 b0 = *(const uint4*)(Bb + (size_t)(n0 + r0) * 256 + k0 + kc0);
        uint4 b1 = *(const uint4*)(Bb + (size_t)(n0 + r0 + 64) * 256 + k0 + kc0);
        __syncthreads();
        *(uint4*)&As[r0][kc0] = a0;
        *(uint4*)&As[r0 + 64][kc0] = a1;
        *(uint4*)&Bs[r0][kc0] = b0;
        *(uint4*)&Bs[r0 + 64][kc0] = b1;
        __syncthreads();
        bf16x8 af[4], bfv[4];
        #pragma unroll
        for (int i = 0; i < 4; ++i) af[i] = *(const bf16x8*)&As[wr * 64 + i * 16 + l16][quad * 8];
        #pragma unroll
        for (int j = 0; j < 4; ++j) bfv[j] = *(const bf16x8*)&Bs[wc * 64 + j * 16 + l16][quad * 8];
        #pragma unroll
        for (int i = 0; i < 4; ++i)
            #pragma unroll
            for (int j = 0; j < 4; ++j)
                acc[i][j] = __builtin_amdgcn_mfma_f32_16x16x32_bf16(af[i], bfv[j], acc[i][j], 0, 0, 0);
    }
    unsigned short* Cb = KVall + ((size_t)l * BN + b) * NP * 512;
    #pragma unroll
    for (int i = 0; i < 4; ++i) {
        #pragma unroll
        for (int r = 0; r < 4; ++r) {
            int m = m0 + wr * 64 + i * 16 + quad * 4 + r;
            #pragma unroll
            for (int j = 0; j < 4; ++j) {
                int n = n0 + wc * 64 + j * 16 + l16;
                Cb[(size_t)m * 512 + n] = f2bf(acc[i][j][r] + bias[n]);
            }
        }
    }
}

// ---------------------------------------------------------------- q0 = act(unmono(xm).reshape(B,8,64) @ Wpc.T + bpc)
__global__ __launch_bounds__(256) void pc_kernel(const unsigned* __restrict__ xmk, const float* __restrict__ Wpc,
                                                 const float* __restrict__ bpc, float* __restrict__ q) {
    int id = blockIdx.x * 256 + threadIdx.x;
    int p = id & 255;
    int rowi = id >> 8;
    int b = rowi >> 3, i = rowi & 7;
    const unsigned* xr = xmk + b * 512 + i * 64;
    const float* w = Wpc + (size_t)p * 64;
    float acc = bpc[p];
    #pragma unroll
    for (int e = 0; e < 64; ++e) acc += funmono(xr[e]) * w[e];
    q[id] = acc > 0.f ? acc : 0.2f * acc;
}

// ---------------------------------------------------------------- memB = bf16(act(x @ Wpi.T + bpi))
__global__ __launch_bounds__(256) void mem_kernel(const float* __restrict__ x, const float* __restrict__ Wpi,
                                                  const float* __restrict__ bpi, unsigned short* __restrict__ memB) {
    size_t id = (size_t)blockIdx.x * 256 + threadIdx.x;
    int p = (int)(id & 255);
    size_t pt = id >> 8;
    float x0 = x[pt * 3 + 0], x1 = x[pt * 3 + 1], x2 = x[pt * 3 + 2];
    float v = bpi[p] + x0 * Wpi[p * 3 + 0] + x1 * Wpi[p * 3 + 1] + x2 * Wpi[p * 3 + 2];
    v = v > 0.f ? v : 0.2f * v;
    memB[id] = f2bf(v);
}

// ---------------------------------------------------------------- fused QKV projections (self-attn)
__global__ __launch_bounds__(256) void qkv_proj_kernel(const float* __restrict__ in,
                                                       const float* __restrict__ Wq0, const float* __restrict__ bq0,
                                                       const float* __restrict__ Wk0, const float* __restrict__ bk0,
                                                       const float* __restrict__ Wv0, const float* __restrict__ bv0,
                                                       float* __restrict__ Qs, float* __restrict__ Ks,
                                                       float* __restrict__ Vs) {
    int which = blockIdx.y;
    const float* W = (which == 0) ? Wq0 : (which == 1) ? Wk0 : Wv0;
    const float* bb = (which == 0) ? bq0 : (which == 1) ? bk0 : bv0;
    float* out = (which == 0) ? Qs : (which == 1) ? Ks : Vs;
    __shared__ __align__(16) float r[256];
    int row = blockIdx.x, tid = threadIdx.x;
    r[tid] = in[(size_t)row * 256 + tid];
    __syncthreads();
    const float4* w4 = (const float4*)(W + (size_t)tid * 256);
    const float4* r4 = (const float4*)r;
    float acc = bb[tid];
    #pragma unroll 8
    for (int c = 0; c < 64; ++c) {
        float4 a = r4[c], wv = w4[c];
        acc += a.x * wv.x + a.y * wv.y + a.z * wv.z + a.w * wv.w;
    }
    out[(size_t)row * 256 + tid] = acc;
}

// ---------------------------------------------------------------- self-attn + O-proj + res + LN + cross-Q-proj
__global__ __launch_bounds__(256) void attn_ln_kernel(const float* __restrict__ Qs, const float* __restrict__ Ks,
                                                      const float* __restrict__ Vs, const float* __restrict__ Wo,
                                                      const float* __restrict__ bo, const float* __restrict__ res,
                                                      const float* __restrict__ g, const float* __restrict__ bt,
                                                      const float* __restrict__ Wq1, const float* __restrict__ bq1,
                                                      float* __restrict__ out, float* __restrict__ Qc) {
    int row = blockIdx.x, tid = threadIdx.x;
    int b = row >> 3;
    __shared__ float Kl[2048], Vl[2048], qr[256];
    __shared__ float sc[64];
    __shared__ __align__(16) float r[256];
    __shared__ __align__(16) float aout[256];
    __shared__ float red[256];
    for (int t = tid; t < 2048; t += 256) {
        Kl[t] = Ks[(size_t)b * 2048 + t];
        Vl[t] = Vs[(size_t)b * 2048 + t];
    }
    qr[tid] = Qs[(size_t)row * 256 + tid];
    __syncthreads();
    const float scale = 0.17677669529663687f;
    if (tid < 64) {
        int h = tid >> 3, k = tid & 7;
        float dot = 0.f;
        #pragma unroll
        for (int d = 0; d < 32; ++d) dot += qr[h * 32 + d] * Kl[k * 256 + h * 32 + d];
        sc[tid] = dot * scale;
    }
    __syncthreads();
    if (tid < 8) {
        float* p = sc + tid * 8;
        float m = -3.4e38f;
        #pragma unroll
        for (int k = 0; k < 8; ++k) m = fmaxf(m, p[k]);
        float s = 0.f;
        #pragma unroll
        for (int k = 0; k < 8; ++k) { p[k] = __expf(p[k] - m); s += p[k]; }
        float inv = 1.f / s;
        #pragma unroll
        for (int k = 0; k < 8; ++k) p[k] *= inv;
    }
    __syncthreads();
    {
        int h = tid >> 5;
        float acc = 0.f;
        #pragma unroll
        for (int k = 0; k < 8; ++k) acc += sc[h * 8 + k] * Vl[k * 256 + tid];
        r[tid] = acc;
    }
    __syncthreads();
    const float4* w4 = (const float4*)(Wo + (size_t)tid * 256);
    const float4* r4 = (const float4*)r;
    float acc = bo[tid];
    #pragma unroll 8
    for (int c = 0; c < 64; ++c) {
        float4 a = r4[c], wv = w4[c];
        acc += a.x * wv.x + a.y * wv.y + a.z * wv.z + a.w * wv.w;
    }
    float v = res[(size_t)row * 256 + tid] + acc;
    red[tid] = v; __syncthreads();
    for (int s = 128; s; s >>= 1) { if (tid < s) red[tid] += red[tid + s]; __syncthreads(); }
    float mean = red[0] * (1.0f / 256.0f);
    __syncthreads();
    float dv = v - mean;
    red[tid] = dv * dv; __syncthreads();
    for (int s = 128; s; s >>= 1) { if (tid < s) red[tid] += red[tid + s]; __syncthreads(); }
    float var = red[0] * (1.0f / 256.0f);
    float oln = g[tid] * dv * rsqrtf(var + 1e-5f) + bt[tid];
    out[(size_t)row * 256 + tid] = oln;
    aout[tid] = oln;
    __syncthreads();
    {
        const float4* wq4 = (const float4*)(Wq1 + (size_t)tid * 256);
        const float4* a4 = (const float4*)aout;
        float qacc = bq1[tid];
        #pragma unroll 8
        for (int c = 0; c < 64; ++c) {
            float4 a = a4[c], wv = wq4[c];
            qacc += a.x * wv.x + a.y * wv.y + a.z * wv.z + a.w * wv.w;
        }
        Qc[(size_t)row * 256 + tid] = qacc;
    }
}

// ---------------------------------------------------------------- cross-attn pass 1: 16 key-blocks of 128
__global__ __launch_bounds__(256) void ca_part_kernel(const float* __restrict__ Qc,
                                                      const unsigned short* __restrict__ KVl,
                                                      float* __restrict__ part) {
    int kb = blockIdx.x, h = blockIdx.y, b = blockIdx.z;
    int tid = threadIdx.x;
    __shared__ float q[8][32];
    __shared__ __align__(16) float S[8][128];
    __shared__ float om[8][8][32];
    const float scale = 0.17677669529663687f;
    {
        int i = tid >> 5, d = tid & 31;
        q[i][d] = Qc[(size_t)(b * 8 + i) * 256 + h * 32 + d];
    }
    __syncthreads();
    {
        int kk = tid & 127, half = tid >> 7;
        int k = kb * 128 + kk;
        const unsigned short* kp = KVl + ((size_t)b * NP + k) * 512 + h * 32;
        float kd[32];
        #pragma unroll
        for (int u = 0; u < 4; ++u) {
            uint4 raw = *(const uint4*)(kp + u * 8);
            unsigned w0 = raw.x, w1 = raw.y, w2 = raw.z, w3 = raw.w;
            kd[u * 8 + 0] = __uint_as_float(w0 << 16); kd[u * 8 + 1] = __uint_as_float(w0 & 0xFFFF0000u);
            kd[u * 8 + 2] = __uint_as_float(w1 << 16); kd[u * 8 + 3] = __uint_as_float(w1 & 0xFFFF0000u);
            kd[u * 8 + 4] = __uint_as_float(w2 << 16); kd[u * 8 + 5] = __uint_as_float(w2 & 0xFFFF0000u);
            kd[u * 8 + 6] = __uint_as_float(w3 << 16); kd[u * 8 + 7] = __uint_as_float(w3 & 0xFFFF0000u);
        }
        #pragma unroll
        for (int i = 0; i < 4; ++i) {
            int ri = half * 4 + i;
            float dot = 0.f;
            #pragma unroll
            for (int d = 0; d < 32; ++d) dot += q[ri][d] * kd[d];
            S[ri][kk] = dot * scale;
        }
    }
    __syncthreads();
    float* pout = part + (((size_t)(b * NH + h)) * 16 + kb) * 288;
    {
        int i = tid >> 5, l32 = tid & 31;
        float m = -3.4e38f;
        #pragma unroll
        for (int t = 0; t < 4; ++t) m = fmaxf(m, S[i][l32 + t * 32]);
        #pragma unroll
        for (int off = 16; off; off >>= 1) m = fmaxf(m, __shfl_xor(m, off));
        float s = 0.f;
        #pragma unroll
        for (int t = 0; t < 4; ++t) {
            float e = __expf(S[i][l32 + t * 32] - m);
            S[i][l32 + t * 32] = e;
            s += e;
        }
        #pragma unroll
        for (int off = 16; off; off >>= 1) s += __shfl_xor(s, off);
        if (l32 == 0) { pout[i] = m; pout[8 + i] = s; }
    }
    __syncthreads();
    {
        int d = tid & 31, grp = tid >> 5;
        const unsigned short* Vb = KVl + ((size_t)b * NP + kb * 128) * 512 + 256 + h * 32 + d;
        float acc[8] = {};
        #pragma unroll 4
        for (int t = 0; t < 16; ++t) {
            int kk = grp * 16 + t;
            float v = bf2f(Vb[(size_t)kk * 512]);
            #pragma unroll
            for (int i = 0; i < 8; ++i) acc[i] += S[i][kk] * v;
        }
        #pragma unroll
        for (int i = 0; i < 8; ++i) om[grp][i][d] = acc[i];
    }
    __syncthreads();
    {
        int i = tid >> 5, d = tid & 31;
        float sum = 0.f;
        #pragma unroll
        for (int g = 0; g < 8; ++g) sum += om[g][i][d];
        pout[16 + i * 32 + d] = sum;
    }
}

// ---------------------------------------------------------------- combine + O-proj + LN + FF + LN [+ final LN+Wcm]
__global__ __launch_bounds__(256) void combine_ff_kernel(const float* __restrict__ part, const float* __restrict__ Wo,
                                                         const float* __restrict__ bo, const float* __restrict__ res,
                                                         const float* __restrict__ g2, const float* __restrict__ b2t,
                                                         const float* __restrict__ W1, const float* __restrict__ b1,
                                                         const float* __restrict__ W2, const float* __restrict__ b2,
                                                         const float* __restrict__ g3, const float* __restrict__ b3t,
                                                         float* __restrict__ out,
                                                         int is_last, const float* __restrict__ lnfg,
                                                         const float* __restrict__ lnfb, const float* __restrict__ Wcm,
                                                         const float* __restrict__ bcm, float* __restrict__ finout) {
    int row = blockIdx.x, tid = threadIdx.x;
    int b = row >> 3, i = row & 7;
    __shared__ __align__(16) float r[256];
    __shared__ __align__(16) float a[256];
    __shared__ __align__(16) float hbuf[512];
    __shared__ float red[256];
    {
        int h = tid >> 5, d = tid & 31;
        const float* pb = part + (size_t)(b * NH + h) * 16 * 288;
        float M = -3.4e38f;
        #pragma unroll
        for (int kb = 0; kb < 16; ++kb) M = fmaxf(M, pb[kb * 288 + i]);
        float L = 0.f, O = 0.f;
        #pragma unroll
        for (int kb = 0; kb < 16; ++kb) {
            float w = __expf(pb[kb * 288 + i] - M);
            L += pb[kb * 288 + 8 + i] * w;
            O += pb[kb * 288 + 16 + i * 32 + d] * w;
        }
        r[tid] = O / L;
    }
    __syncthreads();
    {
        const float4* w4 = (const float4*)(Wo + (size_t)tid * 256);
        const float4* r4 = (const float4*)r;
        float acc = bo[tid];
        #pragma unroll 8
        for (int c = 0; c < 64; ++c) {
            float4 av = r4[c], wv = w4[c];
            acc += av.x * wv.x + av.y * wv.y + av.z * wv.z + av.w * wv.w;
        }
        float v = res[(size_t)row * 256 + tid] + acc;
        red[tid] = v; __syncthreads();
        for (int s = 128; s; s >>= 1) { if (tid < s) red[tid] += red[tid + s]; __syncthreads(); }
        float mean = red[0] * (1.0f / 256.0f);
        __syncthreads();
        float dv = v - mean;
        red[tid] = dv * dv; __syncthreads();
        for (int s = 128; s; s >>= 1) { if (tid < s) red[tid] += red[tid + s]; __syncthreads(); }
        float var = red[0] * (1.0f / 256.0f);
        a[tid] = g2[tid] * dv * rsqrtf(var + 1e-5f) + b2t[tid];
    }
    __syncthreads();
    {
        const float4* a4 = (const float4*)a;
        #pragma unroll
        for (int half = 0; half < 2; ++half) {
            int o = tid + half * 256;
            const float4* w4 = (const float4*)(W1 + (size_t)o * 256);
            float acc = b1[o];
            #pragma unroll 8
            for (int c = 0; c < 64; ++c) {
                float4 av = a4[c], wv = w4[c];
                acc += av.x * wv.x + av.y * wv.y + av.z * wv.z + av.w * wv.w;
            }
            hbuf[o] = acc > 0.f ? acc : 0.2f * acc;
        }
    }
    __syncthreads();
    float tln;
    {
        const float4* h4 = (const float4*)hbuf;
        const float4* w4 = (const float4*)(W2 + (size_t)tid * 512);
        float acc = b2[tid];
        #pragma unroll 8
        for (int c = 0; c < 128; ++c) {
            float4 av = h4[c], wv = w4[c];
            acc += av.x * wv.x + av.y * wv.y + av.z * wv.z + av.w * wv.w;
        }
        float v = a[tid] + acc;
        red[tid] = v; __syncthreads();
        for (int s = 128; s; s >>= 1) { if (tid < s) red[tid] += red[tid + s]; __syncthreads(); }
        float mean = red[0] * (1.0f / 256.0f);
        __syncthreads();
        float dv = v - mean;
        red[tid] = dv * dv; __syncthreads();
        for (int s = 128; s; s >>= 1) { if (tid < s) red[tid] += red[tid + s]; __syncthreads(); }
        float var = red[0] * (1.0f / 256.0f);
        tln = g3[tid] * dv * rsqrtf(var + 1e-5f) + b3t[tid];
    }
    if (!is_last) {
        out[(size_t)row * 256 + tid] = tln;
        return;
    }
    __syncthreads();
    red[tid] = tln; __syncthreads();
    for (int s = 128; s; s >>= 1) { if (tid < s) red[tid] += red[tid + s]; __syncthreads(); }
    float mean = red[0] * (1.0f / 256.0f);
    __syncthreads();
    float dv = tln - mean;
    red[tid] = dv * dv; __syncthreads();
    for (int s = 128; s; s >>= 1) { if (tid < s) red[tid] += red[tid + s]; __syncthreads(); }
    float var = red[0] * (1.0f / 256.0f);
    a[tid] = lnfg[tid] * dv * rsqrtf(var + 1e-5f) + lnfb[tid];
    __syncthreads();
    if (tid < 64) {
        const float4* w4 = (const float4*)(Wcm + (size_t)tid * 256);
        const float4* a4 = (const float4*)a;
        float acc = bcm[tid];
        #pragma unroll 8
        for (int c = 0; c < 64; ++c) {
            float4 av = a4[c], wv = w4[c];
            acc += av.x * wv.x + av.y * wv.y + av.z * wv.z + av.w * wv.w;
        }
        finout[(size_t)b * 512 + i * 64 + tid] = acc;
    }
}

// ================================================================ host
extern "C" void kernel_launch(void* const* d_in, const int* in_sizes, int n_in,
                              void* d_out, int out_size, void* d_ws, size_t ws_size,
                              hipStream_t stream) {
    const float* x    = (const float*)d_in[0];
    const float* Wec  = (const float*)d_in[1];
    const float* bec  = (const float*)d_in[2];
    const float* Wc1  = (const float*)d_in[3];
    const float* bc1  = (const float*)d_in[4];
    const float* Wc2  = (const float*)d_in[5];
    const float* bc2  = (const float*)d_in[6];
    const float* Wc3  = (const float*)d_in[7];
    const float* bc3  = (const float*)d_in[8];
    const float* Wf   = (const float*)d_in[9];
    const float* bf   = (const float*)d_in[10];
    const float* Wpc  = (const float*)d_in[11];
    const float* bpc  = (const float*)d_in[12];
    const float* Wpi  = (const float*)d_in[13];
    const float* bpi  = (const float*)d_in[14];
    const float* Wq   = (const float*)d_in[15];
    const float* bq   = (const float*)d_in[16];
    const float* Wk   = (const float*)d_in[17];
    const float* bk   = (const float*)d_in[18];
    const float* Wv   = (const float*)d_in[19];
    const float* bv   = (const float*)d_in[20];
    const float* Wo   = (const float*)d_in[21];
    const float* bo   = (const float*)d_in[22];
    const float* ln1g = (const float*)d_in[23];
    const float* ln1b = (const float*)d_in[24];
    const float* ln2g = (const float*)d_in[25];
    const float* ln2b = (const float*)d_in[26];
    const float* Wff1 = (const float*)d_in[27];
    const float* bff1 = (const float*)d_in[28];
    const float* Wff2 = (const float*)d_in[29];
    const float* bff2 = (const float*)d_in[30];
    const float* ln3g = (const float*)d_in[31];
    const float* ln3b = (const float*)d_in[32];
    const float* lnfg = (const float*)d_in[33];
    const float* lnfb = (const float*)d_in[34];
    const float* Wcm  = (const float*)d_in[35];
    const float* bcm  = (const float*)d_in[36];
    float* out = (float*)d_out;

    float* ws = (float*)d_ws;
    size_t off = 0;
    auto alloc = [&](size_t n) { float* p = ws + off; off += (n + 3) & ~(size_t)3; return p; };
    int*            idx   = (int*)alloc((size_t)BN * NP * KNN);
    unsigned short* hcatT = (unsigned short*)alloc((size_t)BN * NP * 512 / 2);
    unsigned short* poolT = (unsigned short*)alloc((size_t)BN * NP * 128 / 2);
    unsigned short* WfB   = (unsigned short*)alloc(262144 / 2);
    unsigned short* Wc1B  = (unsigned short*)alloc(4096 / 2);
    unsigned short* Wc2B  = (unsigned short*)alloc(8192 / 2);
    unsigned short* Wc3B  = (unsigned short*)alloc(32768 / 2);
    unsigned short* WkvB  = (unsigned short*)alloc(524288 / 2);
    float*          bkv   = alloc(2048);
    unsigned short* memB  = (unsigned short*)alloc((size_t)BN * NP * 256 / 2);
    unsigned short* KVall = (unsigned short*)alloc((size_t)NL * BN * NP * 512 / 2);
    unsigned*       xmk   = (unsigned*)alloc((size_t)BN * 512);
    float*          qa    = alloc((size_t)BN * 8 * 256);
    float*          qb    = alloc((size_t)BN * 8 * 256);
    float*          Qs    = alloc((size_t)BN * 8 * 256);
    float*          Ks    = alloc((size_t)BN * 8 * 256);
    float*          Vs    = alloc((size_t)BN * 8 * 256);
    float*          Qc    = alloc((size_t)BN * 8 * 256);
    float*          part  = alloc((size_t)BN * NH * 16 * 288);

    // ---- weight casts + xm-key init (no deps) ----
    wcast_kernel<<<3272, 256, 0, stream>>>(Wf, Wc3, Wk, Wv, bk, bv, Wc1, Wc2,
                                           WfB, Wc3B, WkvB, bkv, Wc1B, Wc2B, xmk);

    // ---- point-cloud encoder (all-bf16 [pt][ch] chain) ----
    knn_kernel<<<BN * NP / 4, 256, 0, stream>>>(x, idx);
    edge_conv_kernel<<<BN * NP / 4, 256, 0, stream>>>(x, idx, Wec, bec, hcatT);

    pool_bf16_kernel<<<BN * NP / 4, 256, 0, stream>>>(hcatT, 0, idx, poolT, 64);
    mfma_conv64_kernel<<<dim3(NP / 128, 1, BN), 256, 0, stream>>>(poolT, Wc1B, bc1, hcatT, 64);
    pool_bf16_kernel<<<BN * NP / 4, 256, 0, stream>>>(hcatT, 64, idx, poolT, 64);
    mfma_gemm_kernel<<<dim3(NP / 128, 1, BN), 256, 0, stream>>>(poolT, (size_t)NP * 64, Wc2B, 0,
                                                                bc2, 0, (void*)(hcatT + 128), (size_t)NP * 512, 512,
                                                                64, 1, 1, nullptr, 0);
    pool_bf16_kernel<<<BN * NP / 4, 256, 0, stream>>>(hcatT, 128, idx, poolT, 128);
    mfma_gemm_kernel<<<dim3(NP / 128, 2, BN), 256, 0, stream>>>(poolT, (size_t)NP * 128, Wc3B, 0,
                                                                bc3, 0, (void*)(hcatT + 256), (size_t)NP * 512, 512,
                                                                128, 1, 1, nullptr, 0);
    mfma_gemm_kernel<<<dim3(4, NP / 128, BN), 256, 0, stream>>>(WfB, 0, hcatT, (size_t)NP * 512,
                                                                bf, 1, nullptr, 0, 0,
                                                                512, 0, 0, xmk, 1);
    pc_kernel<<<BN * 8, 256, 0, stream>>>(xmk, Wpc, bpc, qa);
    mem_kernel<<<BN * NP, 256, 0, stream>>>(x, Wpi, bpi, memB);
    mfma_kv_all_kernel<<<dim3(NP / 128, 4 * NL, BN), 256, 0, stream>>>(memB, WkvB, bkv, KVall);

    // ---- transformer layers ----
    float* qcur = qa; float* qnxt = qb;
    for (int l = 0; l < NL; ++l) {
        const float* Wq0 = Wq + (size_t)(l * 2 + 0) * 65536; const float* bq0 = bq + (l * 2 + 0) * 256;
        const float* Wk0 = Wk + (size_t)(l * 2 + 0) * 65536; const float* bk0 = bk + (l * 2 + 0) * 256;
        const float* Wv0 = Wv + (size_t)(l * 2 + 0) * 65536; const float* bv0 = bv + (l * 2 + 0) * 256;
        const float* Wo0 = Wo + (size_t)(l * 2 + 0) * 65536; const float* bo0 = bo + (l * 2 + 0) * 256;
        const float* Wq1 = Wq + (size_t)(l * 2 + 1) * 65536; const float* bq1 = bq + (l * 2 + 1) * 256;
        const float* Wo1 = Wo + (size_t)(l * 2 + 1) * 65536; const float* bo1 = bo + (l * 2 + 1) * 256;
        int last = (l == NL - 1);

        qkv_proj_kernel<<<dim3(BN * 8, 3), 256, 0, stream>>>(qcur, Wq0, bq0, Wk0, bk0, Wv0, bv0, Qs, Ks, Vs);
        attn_ln_kernel<<<BN * 8, 256, 0, stream>>>(Qs, Ks, Vs, Wo0, bo0, qcur,
                                                   ln1g + l * 256, ln1b + l * 256, Wq1, bq1, qnxt, Qc);
        ca_part_kernel<<<dim3(16, NH, BN), 256, 0, stream>>>(Qc, KVall + (size_t)l * BN * NP * 512, part);
        combine_ff_kernel<<<BN * 8, 256, 0, stream>>>(part, Wo1, bo1, qnxt,
                                                      ln2g + l * 256, ln2b + l * 256,
                                                      Wff1 + (size_t)l * 512 * 256, bff1 + l * 512,
                                                      Wff2 + (size_t)l * 256 * 512, bff2 + l * 256,
                                                      ln3g + l * 256, ln3b + l * 256, qcur,
                                                      last, lnfg, lnfb, Wcm, bcm, out);
    }

    (void)in_sizes; (void)n_in; (void)out_size; (void)ws_size; (void)qnxt;
}